// Round 9
// baseline (178.148 us; speedup 1.0000x reference)
//
#include <hip/hip_runtime.h>
#include <hip/hip_bf16.h>
#include <math.h>

// x[32,512,64,64] f32; w1[32,512] f32; w2[512,32] f32.
// Bit-replication of the numpy-fp32 reference pipeline (round-4 PASSED, absmax 0.0).
// ROUND 9 = PROBE ROUND: gather launched 3x (idempotent plane copy -> identical
// output). dur delta vs round 8 (100.8us) = 2x warm-gather time. This splits the
// ~25us model-vs-measurement gap between pool and gather for targeted round 10.

#define C1 512
#define C2 256
#define CMID 32
#define HW 4096   // 64*64
#define B 32

typedef float f32x4 __attribute__((ext_vector_type(4)));

__device__ float g_y[B * C1];     // pooled means, fp32 (numpy-bit-exact)
__device__ int   g_idx[B * C2];   // top-256 channel indices per batch

// ---------------- Kernel 1: numpy-pairwise mean, one wave per channel ----------------
__global__ __launch_bounds__(256) void pool_np_kernel(const float* __restrict__ x) {
    int bc = blockIdx.x * 4 + (threadIdx.x >> 6);   // channel 0..16383
    int L = threadIdx.x & 63;
    const float* a = x + (size_t)bc * HW;
    const float* base = a + (L >> 1) * 128 + (L & 1) * 4;
    f32x4 r = *(const f32x4*)base;
#pragma unroll
    for (int i = 1; i < 16; ++i) {
        f32x4 v = *(const f32x4*)(base + 8 * i);
        r.x = __fadd_rn(r.x, v.x);
        r.y = __fadd_rn(r.y, v.y);
        r.z = __fadd_rn(r.z, v.z);
        r.w = __fadd_rn(r.w, v.w);
    }
    float s = __fadd_rn(__fadd_rn(r.x, r.y), __fadd_rn(r.z, r.w));
    s = __fadd_rn(s, __shfl_xor(s, 1));    // lane0 chain + lane1 chain
    s = __fadd_rn(s, __shfl_xor(s, 2));    // perfect tree over the 32 blocks
    s = __fadd_rn(s, __shfl_xor(s, 4));
    s = __fadd_rn(s, __shfl_xor(s, 8));
    s = __fadd_rn(s, __shfl_xor(s, 16));
    s = __fadd_rn(s, __shfl_xor(s, 32));
    if (L == 0) g_y[bc] = __fdiv_rn(s, 4096.0f);
}

// numpy einsum SSE sum_of_products_contig_two: single __m128 accumulator;
// per 8-chunk: acc += p[0:4]; acc += p[4:8]; final (L0+L1)+(L2+L3).
__device__ __forceinline__ float dot_sse(const float* __restrict__ u,
                                         const float* __restrict__ v, int n) {
    float L0 = 0.f, L1 = 0.f, L2 = 0.f, L3 = 0.f;
    for (int c = 0; c < n; c += 8) {
        L0 = __fadd_rn(L0, __fmul_rn(u[c+0], v[c+0]));
        L1 = __fadd_rn(L1, __fmul_rn(u[c+1], v[c+1]));
        L2 = __fadd_rn(L2, __fmul_rn(u[c+2], v[c+2]));
        L3 = __fadd_rn(L3, __fmul_rn(u[c+3], v[c+3]));
        L0 = __fadd_rn(L0, __fmul_rn(u[c+4], v[c+4]));
        L1 = __fadd_rn(L1, __fmul_rn(u[c+5], v[c+5]));
        L2 = __fadd_rn(L2, __fmul_rn(u[c+6], v[c+6]));
        L3 = __fadd_rn(L3, __fmul_rn(u[c+7], v[c+7]));
    }
    return __fadd_rn(__fadd_rn(L0, L1), __fadd_rn(L2, L3));
}

// ---------------- Kernel 2: SE MLP (fp32 numpy-replica) + stable rank ----------------
__global__ __launch_bounds__(512) void se_np_kernel(const float* __restrict__ w1,
                                                    const float* __restrict__ w2) {
    int b = blockIdx.x;        // 0..31
    int t = threadIdx.x;       // 0..511
    __shared__ float ys[C1];
    __shared__ float hs[CMID];
    __shared__ float ss[C1];

    ys[t] = g_y[b * C1 + t];
    __syncthreads();

    // Layer 1: 32 rows x 4 independent SSE chains (numpy L0..L3), thread = (row,k)
    if (t < CMID * 4) {
        int row = t >> 2, k = t & 3;
        const float* v = w1 + row * C1;
        float Lk = 0.f;
        for (int c = 0; c < C1; c += 8) {
            Lk = __fadd_rn(Lk, __fmul_rn(ys[c + k],     v[c + k]));
            Lk = __fadd_rn(Lk, __fmul_rn(ys[c + 4 + k], v[c + 4 + k]));
        }
        Lk = __fadd_rn(Lk, __shfl_xor(Lk, 1));   // (L0+L1),(L2+L3)
        Lk = __fadd_rn(Lk, __shfl_xor(Lk, 2));   // final combine
        if (k == 0) hs[row] = Lk > 0.0f ? Lk : 0.0f;   // np.maximum(z, 0)
    }
    __syncthreads();

    {
        float z = dot_sse(hs, w2 + t * CMID, CMID);
        float e = (float)exp((double)(-z));      // correctly-rounded fp32 exp
        ss[t] = __fdiv_rn(1.0f, __fadd_rn(1.0f, e));
    }
    __syncthreads();

    // stable argsort(-s): rank = #{s' > s} + #{equal with smaller index}
    float sc = ss[t];
    int rank = 0;
#pragma unroll 8
    for (int c = 0; c < C1; ++c) {
        float v = ss[c];
        rank += (int)((v > sc) || (v == sc && c < t));
    }
    if (rank < C2) g_idx[b * C2 + rank] = t;
}

// ---------------- Kernel 3: gather, half-plane per block (full residency) ----------------
__global__ __launch_bounds__(256) void gather_kernel(const float* __restrict__ x,
                                                     float* __restrict__ out) {
    int bid  = blockIdx.x >> 1;                // plane 0..1023 (b*C2 + r)
    int half = blockIdx.x & 1;                 // 0: first 8 KB, 1: second 8 KB
    int b = bid >> 8;
    int c = g_idx[bid];
    const f32x4* src = (const f32x4*)(x + ((size_t)(b * C1 + c)) * HW);
    f32x4* dst = (f32x4*)(out + (size_t)bid * HW);
    int j = half * 512 + threadIdx.x;          // float4 index within plane
    f32x4 v0 = src[j];
    f32x4 v1 = src[j + 256];
    __builtin_nontemporal_store(v0, &dst[j]);
    __builtin_nontemporal_store(v1, &dst[j + 256]);
}

extern "C" void kernel_launch(void* const* d_in, const int* in_sizes, int n_in,
                              void* d_out, int out_size, void* d_ws, size_t ws_size,
                              hipStream_t stream) {
    const float* x  = (const float*)d_in[0];
    const float* w1 = (const float*)d_in[1];
    const float* w2 = (const float*)d_in[2];
    float* out = (float*)d_out;

    pool_np_kernel<<<B * C1 / 4, 256, 0, stream>>>(x);
    se_np_kernel<<<B, C1, 0, stream>>>(w1, w2);
    // PROBE: 3x identical gather (idempotent). delta vs round 8 = 2x warm-gather.
    gather_kernel<<<B * C2 * 2, 256, 0, stream>>>(x, out);
    gather_kernel<<<B * C2 * 2, 256, 0, stream>>>(x, out);
    gather_kernel<<<B * C2 * 2, 256, 0, stream>>>(x, out);
}

// Round 10
// 101.335 us; speedup vs baseline: 1.7580x; 1.7580x over previous
//
#include <hip/hip_runtime.h>
#include <hip/hip_bf16.h>
#include <math.h>

// x[32,512,64,64] f32; w1[32,512] f32; w2[512,32] f32.
// Bit-replication of the numpy-fp32 reference pipeline (round-4 PASSED, absmax 0.0):
//   y = np.mean(x,(2,3))             -> numpy pairwise_sum (128-blocks, 8 accums, tree)
//   h = relu(np.einsum('bc,rc->br')) -> SSE sum-of-products (mod-4 lanes, (L0+L1)+(L2+L3))
//   s = 1/(1+np.exp(-z))             -> correctly-rounded fp32 exp via fp64, fp32 add/div
//   idx = argsort(-s, stable)[:, :256]; out = take_along_axis(x, idx)
// Round 10: pool restructured -- fully-coalesced global loads (1KB/wave-instr,
// every line fetched once) staged through XOR-swizzled LDS, then the IDENTICAL
// numpy chain arithmetic reads from LDS. Round-9 probe showed warm gather =
// 38.7us (at BW ceiling, L3 gives no read boost) => slack was pool's 32B-granule
// 512B-stride pattern (2-4x line-lookups per byte). Gather back to single launch.

#define C1 512
#define C2 256
#define CMID 32
#define HW 4096   // 64*64
#define B 32

typedef float f32x4 __attribute__((ext_vector_type(4)));

__device__ float g_y[B * C1];     // pooled means, fp32 (numpy-bit-exact)
__device__ int   g_idx[B * C2];   // top-256 channel indices per batch

// 16B-unit swizzle: XOR low 3 bits of unit index with (m & 7) (bits 5..7 = block).
// Write (u = 64k + L) and read (u = 32m + 2i + h) are both conflict-free.
#define SWZ(u) ((u) ^ (((u) >> 5) & 7))

// ---------------- Kernel 1: numpy-pairwise mean, LDS-staged coalesced ----------------
// Plane = 4096 floats = 32 blocks (m) x 16 rows (i) x 2 halves (h) x 4 floats.
// numpy: 8 accumulators r_j per block, r_j += a[8i+j] i=1..15 (sequential), then
// ((r0+r1)+(r2+r3))+((r4+r5)+(r6+r7)), then perfect binary tree over 32 blocks.
// Lane-pair (2m,2m+1) owns block m: lane holds r[4h..4h+3] as f32x4 (identical to
// round-8 kernel; only the data SOURCE changed global->LDS).
__global__ __launch_bounds__(256) void pool_np_kernel(const float* __restrict__ x) {
    __shared__ f32x4 lds[4 * 1024];                 // 4 planes x 16 KB = 64 KB
    int w = threadIdx.x >> 6;                       // wave 0..3 -> plane w
    int L = threadIdx.x & 63;
    int bc = blockIdx.x * 4 + w;                    // channel 0..16383
    const f32x4* src = (const f32x4*)(x + (size_t)bc * HW);
    f32x4* buf = lds + w * 1024;

    // coalesced load: wave instr k reads 1KB contiguous (lane L -> unit 64k+L)
    f32x4 v[16];
#pragma unroll
    for (int k = 0; k < 16; ++k)
        v[k] = src[k * 64 + L];
#pragma unroll
    for (int k = 0; k < 16; ++k) {
        int u = k * 64 + L;
        buf[SWZ(u)] = v[k];
    }
    __syncthreads();                                // LDS visibility (cheap, once)

    // identical numpy chain, sourced from LDS: unit(m,i,h) = 32m + 2i + h
    int m = L >> 1, h = L & 1;
    int ubase = 32 * m + h;
    f32x4 r = buf[SWZ(ubase)];
#pragma unroll
    for (int i = 1; i < 16; ++i) {
        f32x4 t = buf[SWZ(ubase + 2 * i)];
        r.x = __fadd_rn(r.x, t.x);
        r.y = __fadd_rn(r.y, t.y);
        r.z = __fadd_rn(r.z, t.z);
        r.w = __fadd_rn(r.w, t.w);
    }
    float s = __fadd_rn(__fadd_rn(r.x, r.y), __fadd_rn(r.z, r.w));
    s = __fadd_rn(s, __shfl_xor(s, 1));    // lane0 chain + lane1 chain
    s = __fadd_rn(s, __shfl_xor(s, 2));    // perfect tree over the 32 blocks
    s = __fadd_rn(s, __shfl_xor(s, 4));
    s = __fadd_rn(s, __shfl_xor(s, 8));
    s = __fadd_rn(s, __shfl_xor(s, 16));
    s = __fadd_rn(s, __shfl_xor(s, 32));
    if (L == 0) g_y[bc] = __fdiv_rn(s, 4096.0f);
}

// numpy einsum SSE sum_of_products_contig_two: single __m128 accumulator;
// per 8-chunk: acc += p[0:4]; acc += p[4:8]; final (L0+L1)+(L2+L3).
__device__ __forceinline__ float dot_sse(const float* __restrict__ u,
                                         const float* __restrict__ v, int n) {
    float L0 = 0.f, L1 = 0.f, L2 = 0.f, L3 = 0.f;
    for (int c = 0; c < n; c += 8) {
        L0 = __fadd_rn(L0, __fmul_rn(u[c+0], v[c+0]));
        L1 = __fadd_rn(L1, __fmul_rn(u[c+1], v[c+1]));
        L2 = __fadd_rn(L2, __fmul_rn(u[c+2], v[c+2]));
        L3 = __fadd_rn(L3, __fmul_rn(u[c+3], v[c+3]));
        L0 = __fadd_rn(L0, __fmul_rn(u[c+4], v[c+4]));
        L1 = __fadd_rn(L1, __fmul_rn(u[c+5], v[c+5]));
        L2 = __fadd_rn(L2, __fmul_rn(u[c+6], v[c+6]));
        L3 = __fadd_rn(L3, __fmul_rn(u[c+7], v[c+7]));
    }
    return __fadd_rn(__fadd_rn(L0, L1), __fadd_rn(L2, L3));
}

// ---------------- Kernel 2: SE MLP (fp32 numpy-replica) + stable rank ----------------
__global__ __launch_bounds__(512) void se_np_kernel(const float* __restrict__ w1,
                                                    const float* __restrict__ w2) {
    int b = blockIdx.x;        // 0..31
    int t = threadIdx.x;       // 0..511
    __shared__ float ys[C1];
    __shared__ float hs[CMID];
    __shared__ float ss[C1];

    ys[t] = g_y[b * C1 + t];
    __syncthreads();

    // Layer 1: 32 rows x 4 independent SSE chains (numpy L0..L3), thread = (row,k)
    if (t < CMID * 4) {
        int row = t >> 2, k = t & 3;
        const float* v = w1 + row * C1;
        float Lk = 0.f;
        for (int c = 0; c < C1; c += 8) {
            Lk = __fadd_rn(Lk, __fmul_rn(ys[c + k],     v[c + k]));
            Lk = __fadd_rn(Lk, __fmul_rn(ys[c + 4 + k], v[c + 4 + k]));
        }
        Lk = __fadd_rn(Lk, __shfl_xor(Lk, 1));   // (L0+L1),(L2+L3)
        Lk = __fadd_rn(Lk, __shfl_xor(Lk, 2));   // final combine
        if (k == 0) hs[row] = Lk > 0.0f ? Lk : 0.0f;   // np.maximum(z, 0)
    }
    __syncthreads();

    {
        float z = dot_sse(hs, w2 + t * CMID, CMID);
        float e = (float)exp((double)(-z));      // correctly-rounded fp32 exp
        ss[t] = __fdiv_rn(1.0f, __fadd_rn(1.0f, e));
    }
    __syncthreads();

    // stable argsort(-s): rank = #{s' > s} + #{equal with smaller index}
    float sc = ss[t];
    int rank = 0;
#pragma unroll 8
    for (int c = 0; c < C1; ++c) {
        float v = ss[c];
        rank += (int)((v > sc) || (v == sc && c < t));
    }
    if (rank < C2) g_idx[b * C2 + rank] = t;
}

// ---------------- Kernel 3: gather, half-plane per block (full residency) ----------------
__global__ __launch_bounds__(256) void gather_kernel(const float* __restrict__ x,
                                                     float* __restrict__ out) {
    int bid  = blockIdx.x >> 1;                // plane 0..1023 (b*C2 + r)
    int half = blockIdx.x & 1;                 // 0: first 8 KB, 1: second 8 KB
    int b = bid >> 8;
    int c = g_idx[bid];
    const f32x4* src = (const f32x4*)(x + ((size_t)(b * C1 + c)) * HW);
    f32x4* dst = (f32x4*)(out + (size_t)bid * HW);
    int j = half * 512 + threadIdx.x;          // float4 index within plane
    f32x4 v0 = src[j];
    f32x4 v1 = src[j + 256];
    __builtin_nontemporal_store(v0, &dst[j]);
    __builtin_nontemporal_store(v1, &dst[j + 256]);
}

extern "C" void kernel_launch(void* const* d_in, const int* in_sizes, int n_in,
                              void* d_out, int out_size, void* d_ws, size_t ws_size,
                              hipStream_t stream) {
    const float* x  = (const float*)d_in[0];
    const float* w1 = (const float*)d_in[1];
    const float* w2 = (const float*)d_in[2];
    float* out = (float*)d_out;

    pool_np_kernel<<<B * C1 / 4, 256, 0, stream>>>(x);
    se_np_kernel<<<B, C1, 0, stream>>>(w1, w2);
    gather_kernel<<<B * C2 * 2, 256, 0, stream>>>(x, out);
}